// Round 4
// baseline (376.637 us; speedup 1.0000x reference)
//
#include <hip/hip_runtime.h>
#include <math.h>

#define NB 4
#define L 4096
#define D 64
// ws layout (ushorts): qh[16384][64] | ql[16384][64] | K: per batch
// [plane hi/lo][cq 8][col 4096][8 bf16]  (batch stride 524288, plane 262144)
#define WS_QL 1048576
#define WS_K  2097152
#define KBS   524288
#define KPL   262144
// Q pre-scale: 1/TEMPERATURE * log2(e)  -> scores in log2 units (monotone)
#define QSCALE 0.1803368801111243f

typedef __attribute__((ext_vector_type(8))) short short8;   // 8 bf16 = 4 VGPRs
typedef __attribute__((ext_vector_type(4))) float floatx4;

// fp32 -> (hi, lo) bf16 pair: hi = RNE(x), lo = RNE(x - hi) (exact residual).
static __device__ inline ushort2 f2bf2(float x) {
    unsigned int u = __builtin_bit_cast(unsigned int, x);
    unsigned int uh = u + (0x7FFFu + ((u >> 16) & 1u));
    unsigned short h = (unsigned short)(uh >> 16);
    float hf = __builtin_bit_cast(float, (unsigned int)h << 16);
    float r = x - hf;
    unsigned int v = __builtin_bit_cast(unsigned int, r);
    unsigned short l = (unsigned short)((v + (0x7FFFu + ((v >> 16) & 1u))) >> 16);
    ushort2 p; p.x = h; p.y = l; return p;
}

// ---- pre-pass: Q (scaled) and K fp32 -> bf16 hi/lo planes in d_ws
__global__ __launch_bounds__(256)
void convert_kernel(const float* __restrict__ qg, const float* __restrict__ kg,
                    unsigned short* __restrict__ ws) {
    unsigned int i = blockIdx.x * 256 + threadIdx.x;       // 524288 threads
    if (i < 262144) {                                      // Q: 262144 float4
        float4 qv = ((const float4*)qg)[i];
        ushort2 p0 = f2bf2(qv.x * QSCALE), p1 = f2bf2(qv.y * QSCALE),
                p2 = f2bf2(qv.z * QSCALE), p3 = f2bf2(qv.w * QSCALE);
        ushort4 h; h.x = p0.x; h.y = p1.x; h.z = p2.x; h.w = p3.x;
        ushort4 l; l.x = p0.y; l.y = p1.y; l.z = p2.y; l.w = p3.y;
        *(ushort4*)&ws[i * 4] = h;
        *(ushort4*)&ws[WS_QL + i * 4] = l;
    } else {                                               // K: 262144 float4
        unsigned int j = i - 262144;
        float4 kv = ((const float4*)kg)[j];
        ushort2 p0 = f2bf2(kv.x), p1 = f2bf2(kv.y), p2 = f2bf2(kv.z), p3 = f2bf2(kv.w);
        ushort4 h; h.x = p0.x; h.y = p1.x; h.z = p2.x; h.w = p3.x;
        ushort4 l; l.x = p0.y; l.y = p1.y; l.z = p2.y; l.w = p3.y;
        unsigned int bcol = j >> 4;                        // b*4096 + col
        unsigned int f4   = j & 15;
        unsigned int b    = bcol >> 12, col = bcol & 4095;
        unsigned int cq   = f4 >> 1, half = f4 & 1;
        size_t base = WS_K + (size_t)b * KBS + ((size_t)cq * 4096 + col) * 8 + half * 4;
        *(ushort4*)&ws[base] = h;
        *(ushort4*)&ws[base + KPL] = l;
    }
}

#define SENT 0x7FFFFFFF   // sentinel col: loses all lowest-col tie-breaks

__global__ __launch_bounds__(256, 4)
void sparse_attn_kernel(const unsigned short* __restrict__ ws,
                        const float* __restrict__ vg,
                        float* __restrict__ outg) {
    __shared__ float smv[3][16][5];     // foreign-wave top-5 values (slot4 = 5th val)
    __shared__ int   smc[3][16][4];     // foreign-wave top-4 cols

    const int tid  = threadIdx.x;
    const int lane = tid & 63;
    const int wid  = tid >> 6;          // column quarter 0..3
    const int c16  = lane & 15;
    const int quad = lane >> 4;

    // XCD swizzle: consecutive sblk on one XCD -> blocks on one XCD march
    // through the same K window in lockstep (shared sliding window in L2/L1).
    const int sblk  = (blockIdx.x & 7) * 128 + (blockIdx.x >> 3);
    const int qbase = sblk * 16;        // 16 rows per block (shared by 4 waves)
    const int b     = qbase >> 12;

    const unsigned short* qh   = ws;
    const unsigned short* ql   = ws + WS_QL;
    const unsigned short* kbat = ws + WS_K + (size_t)b * KBS;
    const float* vb = vg + (size_t)b * L * D;
    float* attng = outg + (size_t)NB * L * D;

    // ---- Q fragments (loop-invariant): A[m=c16][k=quad*8+j], two K-steps
    const int qrow = qbase + c16;
    const short8 a0h = *(const short8*)&qh[(size_t)qrow * 64 + quad * 8];
    const short8 a1h = *(const short8*)&qh[(size_t)qrow * 64 + 32 + quad * 8];
    const short8 a0l = *(const short8*)&ql[(size_t)qrow * 64 + quad * 8];
    const short8 a1l = *(const short8*)&ql[(size_t)qrow * 64 + 32 + quad * 8];

    float tv[4][5];
    int   tc[4][4];                     // no col for slot 4 (never needed)
#pragma unroll
    for (int r = 0; r < 4; ++r) {
#pragma unroll
        for (int i = 0; i < 5; ++i) tv[r][i] = -INFINITY;
#pragma unroll
        for (int i = 0; i < 4; ++i) tc[r][i] = SENT;
    }

    // Per-wave column quarter; K fragment base pointers (b128, coalesced).
    const int colq = wid * 1024;
    const unsigned short* bp0 = kbat + ((size_t)(quad)     * 4096 + colq + c16) * 8;
    const unsigned short* bp1 = kbat + ((size_t)(4 + quad) * 4096 + colq + c16) * 8;
    const floatx4 zv = {0.f, 0.f, 0.f, 0.f};

    // ---- barrier-free hot loop: 64 groups of 16 columns. NO STORES inside:
    // a store in the loop shares the in-order vmcnt counter with the K loads,
    // so every compiler s_waitcnt guarding an MFMA operand transitively waits
    // for older HBM store-acks — serializing the loop on store latency.
#pragma unroll 4
    for (int cg = 0; cg < 64; ++cg) {
        const int off = cg * 128;                   // 16 cols * 8 ushorts
        short8 b0h = *(const short8*)(bp0 + off);
        short8 b1h = *(const short8*)(bp1 + off);
        short8 b0l = *(const short8*)(bp0 + KPL + off);
        short8 b1l = *(const short8*)(bp1 + KPL + off);
        floatx4 acc = {0.f, 0.f, 0.f, 0.f};
        acc = __builtin_amdgcn_mfma_f32_16x16x32_bf16(a0h, b0h, acc, 0, 0, 0);
        acc = __builtin_amdgcn_mfma_f32_16x16x32_bf16(a1h, b1h, acc, 0, 0, 0);
        acc = __builtin_amdgcn_mfma_f32_16x16x32_bf16(a0l, b0h, acc, 0, 0, 0);
        acc = __builtin_amdgcn_mfma_f32_16x16x32_bf16(a1l, b1h, acc, 0, 0, 0);
        acc = __builtin_amdgcn_mfma_f32_16x16x32_bf16(a0h, b0l, acc, 0, 0, 0);
        acc = __builtin_amdgcn_mfma_f32_16x16x32_bf16(a1h, b1l, acc, 0, 0, 0);

        const int col = colq + cg * 16 + c16;
#pragma unroll
        for (int r = 0; r < 4; ++r) {
            float s = acc[r];                       // pre-scaled score (log2 units)
            bool q0 = s > tv[r][0];
            bool q1 = s > tv[r][1];
            bool q2 = s > tv[r][2];
            bool q3 = s > tv[r][3];
            bool q4 = s > tv[r][4];
            tv[r][4] = q4 ? (q3 ? tv[r][3] : s)   : tv[r][4];
            tv[r][3] = q3 ? (q2 ? tv[r][2] : s)   : tv[r][3];
            tc[r][3] = q3 ? (q2 ? tc[r][2] : col) : tc[r][3];
            tv[r][2] = q2 ? (q1 ? tv[r][1] : s)   : tv[r][2];
            tc[r][2] = q2 ? (q1 ? tc[r][1] : col) : tc[r][2];
            tv[r][1] = q1 ? (q0 ? tv[r][0] : s)   : tv[r][1];
            tc[r][1] = q1 ? (q0 ? tc[r][0] : col) : tc[r][1];
            tv[r][0] = q0 ? s   : tv[r][0];
            tc[r][0] = q0 ? col : tc[r][0];
        }
    }

    // ---- zero-fill burst: this wave's column quarter of all 16 rows.
    // Issued back-to-back; retires asynchronously under stage A's shuffle
    // merge. The __syncthreads() before stage C drains vmcnt(0), preserving
    // zero-before-scatter ordering exactly as before.
    {
        float* zbase = attng + (size_t)qbase * L + colq + lane * 4;
#pragma unroll
        for (int row = 0; row < 16; ++row) {
            float* rp = zbase + (size_t)row * L;
            __builtin_nontemporal_store(zv, (floatx4*)(rp));
            __builtin_nontemporal_store(zv, (floatx4*)(rp + 256));
            __builtin_nontemporal_store(zv, (floatx4*)(rp + 512));
            __builtin_nontemporal_store(zv, (floatx4*)(rp + 768));
        }
    }

    // ---- stage A: merge across the 16 lanes of each quad (rows quad*4+r)
    float gv[4][5]; int gc[4][4];
#pragma unroll
    for (int r = 0; r < 4; ++r) {
#pragma unroll
        for (int k5 = 0; k5 < 4; ++k5) {            // top-4 with cols (pop rounds)
            float cv = tv[r][0]; int cc = tc[r][0];
#pragma unroll
            for (int m = 8; m >= 1; m >>= 1) {
                float ov = __shfl_xor(cv, m, 64);
                int   oc = __shfl_xor(cc, m, 64);
                if (ov > cv || (ov == cv && oc < cc)) { cv = ov; cc = oc; }
            }
            gv[r][k5] = cv; gc[r][k5] = cc;
            if (tc[r][0] == cc && tv[r][0] == cv) { // unique owner pops
                tv[r][0] = tv[r][1]; tc[r][0] = tc[r][1];
                tv[r][1] = tv[r][2]; tc[r][1] = tc[r][2];
                tv[r][2] = tv[r][3]; tc[r][2] = tc[r][3];
                tv[r][3] = tv[r][4]; tc[r][3] = SENT;
                tv[r][4] = -INFINITY;
            }
        }
        float fv = tv[r][0];                        // 5th: value-only max
#pragma unroll
        for (int m = 8; m >= 1; m >>= 1) fv = fmaxf(fv, __shfl_xor(fv, m, 64));
        gv[r][4] = fv;
    }

    // ---- stage B: waves 1-3 deposit per-row records
    if (wid > 0) {
#pragma unroll
        for (int r = 0; r < 4; ++r) {
            const int rowl = quad * 4 + r;
            if (c16 < 4) {
                smv[wid - 1][rowl][c16] = gv[r][c16];
                smc[wid - 1][rowl][c16] = gc[r][c16];
            } else if (c16 == 4) {
                smv[wid - 1][rowl][4] = gv[r][4];
            }
        }
    }
    __syncthreads();    // also drains all zero-fill stores (vmcnt(0) pre-barrier)

    // ---- stage C: wave 0 merges foreign quarters, sparsifies, emits
    if (wid == 0) {
#pragma unroll
        for (int r = 0; r < 4; ++r) {
            const int rowl = quad * 4 + r;
            float lv[5]; int lc[4];
#pragma unroll
            for (int i = 0; i < 5; ++i) lv[i] = gv[r][i];
#pragma unroll
            for (int i = 0; i < 4; ++i) lc[i] = gc[r][i];

#pragma unroll
            for (int f = 0; f < 3; ++f) {
#pragma unroll
                for (int s5 = 0; s5 < 4; ++s5) {    // foreign top-4 (with col)
                    float v = smv[f][rowl][s5];
                    int   c = smc[f][rowl][s5];
                    bool q0 = v > lv[0];
                    bool q1 = v > lv[1];
                    bool q2 = v > lv[2];
                    bool q3 = v > lv[3];
                    bool q4 = v > lv[4];
                    lv[4] = q4 ? (q3 ? lv[3] : v) : lv[4];
                    lv[3] = q3 ? (q2 ? lv[2] : v) : lv[3];
                    lc[3] = q3 ? (q2 ? lc[2] : c) : lc[3];
                    lv[2] = q2 ? (q1 ? lv[1] : v) : lv[2];
                    lc[2] = q2 ? (q1 ? lc[1] : c) : lc[2];
                    lv[1] = q1 ? (q0 ? lv[0] : v) : lv[1];
                    lc[1] = q1 ? (q0 ? lc[0] : c) : lc[1];
                    lv[0] = q0 ? v : lv[0];
                    lc[0] = q0 ? c : lc[0];
                }
                {                                    // foreign 5th: value-only
                    float v = smv[f][rowl][4];
                    bool q0 = v > lv[0];
                    bool q1 = v > lv[1];
                    bool q2 = v > lv[2];
                    bool q3 = v > lv[3];
                    bool q4 = v > lv[4];
                    lv[4] = q4 ? (q3 ? lv[3] : v) : lv[4];
                    lv[3] = q3 ? (q2 ? lv[2] : v) : lv[3];
                    lv[2] = q2 ? (q1 ? lv[1] : v) : lv[2];
                    lv[1] = q1 ? (q0 ? lv[0] : v) : lv[1];
                    lv[0] = q0 ? v : lv[0];
                }
            }

            // sparsify, Z-free: w_i ∝ 2^(s_i - s_5) - 1  (exact ratio; the
            // reference's eps terms contribute <= ~1e-3 relative — see notes)
            float u0 = exp2f(lv[0] - lv[4]) - 1.0f;
            float u1 = exp2f(lv[1] - lv[4]) - 1.0f;
            float u2 = exp2f(lv[2] - lv[4]) - 1.0f;
            float u3 = exp2f(lv[3] - lv[4]) - 1.0f;
            float inv = 1.0f / (u0 + u1 + u2 + u3 + 1e-30f);
            float w0 = u0 * inv, w1 = u1 * inv, w2 = u2 * inv, w3 = u3 * inv;

            const int rowabs = qbase + rowl;

            // V gather (clamped for sentinel cols, whose weight is 0)
            unsigned int i0 = min((unsigned)lc[0], 4095u);
            unsigned int i1 = min((unsigned)lc[1], 4095u);
            unsigned int i2 = min((unsigned)lc[2], 4095u);
            unsigned int i3 = min((unsigned)lc[3], 4095u);
            const float4 v0 = *(const float4*)(vb + (size_t)i0 * D + c16 * 4);
            const float4 v1 = *(const float4*)(vb + (size_t)i1 * D + c16 * 4);
            const float4 v2 = *(const float4*)(vb + (size_t)i2 * D + c16 * 4);
            const float4 v3 = *(const float4*)(vb + (size_t)i3 * D + c16 * 4);
            floatx4 o;
            o.x = w0 * v0.x + w1 * v1.x + w2 * v2.x + w3 * v3.x;
            o.y = w0 * v0.y + w1 * v1.y + w2 * v2.y + w3 * v3.y;
            o.z = w0 * v0.z + w1 * v1.z + w2 * v2.z + w3 * v3.z;
            o.w = w0 * v0.w + w1 * v1.w + w2 * v2.w + w3 * v3.w;
            __builtin_nontemporal_store(o, (floatx4*)(outg + (size_t)rowabs * D + c16 * 4));

            // scatter <=4 nonzeros into the (zeroed) dense attn row
            if (c16 < 4) {
                float wv = c16 == 0 ? w0 : c16 == 1 ? w1 : c16 == 2 ? w2 : w3;
                int   cs = c16 == 0 ? lc[0] : c16 == 1 ? lc[1]
                         : c16 == 2 ? lc[2] : lc[3];
                if ((unsigned)cs < 4096u && wv > 0.f)
                    attng[(size_t)rowabs * L + cs] = wv;
            }
        }
    }
}

extern "C" void kernel_launch(void* const* d_in, const int* in_sizes, int n_in,
                              void* d_out, int out_size, void* d_ws, size_t ws_size,
                              hipStream_t stream) {
    const float* q = (const float*)d_in[0];
    const float* k = (const float*)d_in[1];
    const float* v = (const float*)d_in[2];
    float* out = (float*)d_out;
    unsigned short* ws = (unsigned short*)d_ws;

    // 1) convert Q (pre-scaled) and K fp32 -> bf16 hi/lo planes in d_ws
    convert_kernel<<<2048, 256, 0, stream>>>(q, k, ws);

    // 2) barrier-free sparse attention: 16 rows x 4 col-quarter waves / block
    sparse_attn_kernel<<<1024, 256, 0, stream>>>(ws, v, out);
}

// Round 5
// 310.185 us; speedup vs baseline: 1.2142x; 1.2142x over previous
//
#include <hip/hip_runtime.h>
#include <math.h>

#define NB 4
#define L 4096
#define D 64
// ws layout (ushorts): qh[16384][64] | ql[16384][64] | K: per batch
// [plane hi/lo][cq 8][col 4096][8 bf16]  (batch stride 524288, plane 262144)
#define WS_QL 1048576
#define WS_K  2097152
#define KBS   524288
#define KPL   262144
// Q pre-scale: 1/TEMPERATURE * log2(e)  -> scores in log2 units (monotone)
#define QSCALE 0.1803368801111243f

typedef __attribute__((ext_vector_type(8))) short short8;   // 8 bf16 = 4 VGPRs
typedef __attribute__((ext_vector_type(4))) float floatx4;

// fp32 -> (hi, lo) bf16 pair: hi = RNE(x), lo = RNE(x - hi) (exact residual).
static __device__ inline ushort2 f2bf2(float x) {
    unsigned int u = __builtin_bit_cast(unsigned int, x);
    unsigned int uh = u + (0x7FFFu + ((u >> 16) & 1u));
    unsigned short h = (unsigned short)(uh >> 16);
    float hf = __builtin_bit_cast(float, (unsigned int)h << 16);
    float r = x - hf;
    unsigned int v = __builtin_bit_cast(unsigned int, r);
    unsigned short l = (unsigned short)((v + (0x7FFFu + ((v >> 16) & 1u))) >> 16);
    ushort2 p; p.x = h; p.y = l; return p;
}

// ---- pre-pass: Q (scaled) and K fp32 -> bf16 hi/lo planes in d_ws
__global__ __launch_bounds__(256)
void convert_kernel(const float* __restrict__ qg, const float* __restrict__ kg,
                    unsigned short* __restrict__ ws) {
    unsigned int i = blockIdx.x * 256 + threadIdx.x;       // 524288 threads
    if (i < 262144) {                                      // Q: 262144 float4
        float4 qv = ((const float4*)qg)[i];
        ushort2 p0 = f2bf2(qv.x * QSCALE), p1 = f2bf2(qv.y * QSCALE),
                p2 = f2bf2(qv.z * QSCALE), p3 = f2bf2(qv.w * QSCALE);
        ushort4 h; h.x = p0.x; h.y = p1.x; h.z = p2.x; h.w = p3.x;
        ushort4 l; l.x = p0.y; l.y = p1.y; l.z = p2.y; l.w = p3.y;
        *(ushort4*)&ws[i * 4] = h;
        *(ushort4*)&ws[WS_QL + i * 4] = l;
    } else {                                               // K: 262144 float4
        unsigned int j = i - 262144;
        float4 kv = ((const float4*)kg)[j];
        ushort2 p0 = f2bf2(kv.x), p1 = f2bf2(kv.y), p2 = f2bf2(kv.z), p3 = f2bf2(kv.w);
        ushort4 h; h.x = p0.x; h.y = p1.x; h.z = p2.x; h.w = p3.x;
        ushort4 l; l.x = p0.y; l.y = p1.y; l.z = p2.y; l.w = p3.y;
        unsigned int bcol = j >> 4;                        // b*4096 + col
        unsigned int f4   = j & 15;
        unsigned int b    = bcol >> 12, col = bcol & 4095;
        unsigned int cq   = f4 >> 1, half = f4 & 1;
        size_t base = WS_K + (size_t)b * KBS + ((size_t)cq * 4096 + col) * 8 + half * 4;
        *(ushort4*)&ws[base] = h;
        *(ushort4*)&ws[base + KPL] = l;
    }
}

// ---- tagged top-5 primitives ------------------------------------------------
// Scores carry their column in the low 12 mantissa bits (cleared first):
// tag = 4095-col for s>=0, col for s<0  => float order == (score, lowest col).
// Sorted-descending insert of one value: d0'=max(t,d0), dk'=med3(t,d(k-1),dk).
static __device__ inline void ins5(float d[5], float t) {
    float n0 = fmaxf(d[0], t);
    float n1 = __builtin_amdgcn_fmed3f(t, d[0], d[1]);
    float n2 = __builtin_amdgcn_fmed3f(t, d[1], d[2]);
    float n3 = __builtin_amdgcn_fmed3f(t, d[2], d[3]);
    float n4 = __builtin_amdgcn_fmed3f(t, d[3], d[4]);
    d[0] = n0; d[1] = n1; d[2] = n2; d[3] = n3; d[4] = n4;
}

// Merge a sorted-descending 5-list o into sorted d (top-5 of union).
// o[j] can only land in slots >= j (o[j] <= o[j-1] <= d[j-1] after update):
// 5+4+3+2+1 = 15 VALU.
static __device__ inline void merge5(float d[5], const float o[5]) {
#pragma unroll
    for (int j = 0; j < 5; ++j) {
        float t = o[j];
        float carry = d[j];
        d[j] = fmaxf(d[j], t);
#pragma unroll
        for (int k = j + 1; k < 5; ++k) {
            float pk = d[k];
            d[k] = __builtin_amdgcn_fmed3f(t, carry, d[k]);
            carry = pk;
        }
    }
}

__global__ __launch_bounds__(256, 4)
void sparse_attn_kernel(const unsigned short* __restrict__ ws,
                        const float* __restrict__ vg,
                        float* __restrict__ outg) {
    __shared__ float smv[3][16][5];     // foreign-wave tagged top-5 per row

    const int tid  = threadIdx.x;
    const int lane = tid & 63;
    const int wid  = tid >> 6;          // column quarter 0..3
    const int c16  = lane & 15;
    const int quad = lane >> 4;

    // XCD swizzle: consecutive sblk on one XCD -> blocks on one XCD march
    // through the same K window in lockstep (shared sliding window in L2/L1).
    const int sblk  = (blockIdx.x & 7) * 128 + (blockIdx.x >> 3);
    const int qbase = sblk * 16;        // 16 rows per block (shared by 4 waves)
    const int b     = qbase >> 12;

    const unsigned short* qh   = ws;
    const unsigned short* ql   = ws + WS_QL;
    const unsigned short* kbat = ws + WS_K + (size_t)b * KBS;
    const float* vb = vg + (size_t)b * L * D;
    float* attng = outg + (size_t)NB * L * D;

    // ---- Q fragments (loop-invariant): A[m=c16][k=quad*8+j], two K-steps
    const int qrow = qbase + c16;
    const short8 a0h = *(const short8*)&qh[(size_t)qrow * 64 + quad * 8];
    const short8 a1h = *(const short8*)&qh[(size_t)qrow * 64 + 32 + quad * 8];
    const short8 a0l = *(const short8*)&ql[(size_t)qrow * 64 + quad * 8];
    const short8 a1l = *(const short8*)&ql[(size_t)qrow * 64 + 32 + quad * 8];

    float tv[4][5];                     // tagged top-5 per row (sorted desc)
#pragma unroll
    for (int r = 0; r < 4; ++r)
#pragma unroll
        for (int i = 0; i < 5; ++i) tv[r][i] = -INFINITY;

    // Per-wave column quarter; K fragment base pointers (b128, coalesced).
    const int colq = wid * 1024;
    const int colbase = colq + c16;     // this lane's col for cg=0
    const unsigned short* bp0 = kbat + ((size_t)(quad)     * 4096 + colq + c16) * 8;
    const unsigned short* bp1 = kbat + ((size_t)(4 + quad) * 4096 + colq + c16) * 8;
    const float4 zv = make_float4(0.f, 0.f, 0.f, 0.f);

    // ---- barrier-free hot loop: 64 groups of 16 columns
#pragma unroll 4
    for (int cg = 0; cg < 64; ++cg) {
        const int off = cg * 128;                   // 16 cols * 8 ushorts
        short8 b0h = *(const short8*)(bp0 + off);
        short8 b1h = *(const short8*)(bp1 + off);
        short8 b0l = *(const short8*)(bp0 + KPL + off);
        short8 b1l = *(const short8*)(bp1 + KPL + off);
        floatx4 acc = {0.f, 0.f, 0.f, 0.f};
        acc = __builtin_amdgcn_mfma_f32_16x16x32_bf16(a0h, b0h, acc, 0, 0, 0);
        acc = __builtin_amdgcn_mfma_f32_16x16x32_bf16(a1h, b1h, acc, 0, 0, 0);
        acc = __builtin_amdgcn_mfma_f32_16x16x32_bf16(a0l, b0h, acc, 0, 0, 0);
        acc = __builtin_amdgcn_mfma_f32_16x16x32_bf16(a1l, b1h, acc, 0, 0, 0);
        acc = __builtin_amdgcn_mfma_f32_16x16x32_bf16(a0h, b0l, acc, 0, 0, 0);
        acc = __builtin_amdgcn_mfma_f32_16x16x32_bf16(a1h, b1l, acc, 0, 0, 0);

        // zero-fill one float4 of this block's dense attn region (overlaps)
        {
            int idx = cg * 64 + lane;               // [0, 4096)
            *(float4*)&attng[(size_t)(qbase + (idx >> 8)) * L + colq + (idx & 255) * 4] = zv;
        }

        const int cx = (colbase + cg * 16) ^ 4095;  // tag for s >= 0
#pragma unroll
        for (int r = 0; r < 4; ++r) {
            int si  = __builtin_bit_cast(int, (float)acc[r]);
            int tag = cx ^ ((si >> 31) & 4095);     // s<0: tag flips back to col
            int ti  = (si & 0xFFFFF000) | tag;
            ins5(tv[r], __builtin_bit_cast(float, ti));
        }
    }

    // ---- stage A: butterfly merge across the 16 lanes of each quad
#pragma unroll
    for (int r = 0; r < 4; ++r) {
#pragma unroll
        for (int m = 8; m >= 1; m >>= 1) {
            float o[5];
#pragma unroll
            for (int i = 0; i < 5; ++i) o[i] = __shfl_xor(tv[r][i], m, 64);
            merge5(tv[r], o);
        }
    }

    // ---- stage B: waves 1-3 deposit per-row tagged lists
    if (wid > 0) {
#pragma unroll
        for (int r = 0; r < 4; ++r) {
            const int rowl = quad * 4 + r;
            if (c16 < 5) smv[wid - 1][rowl][c16] = tv[r][c16];
        }
    }
    __syncthreads();    // also drains all zero-fill stores (vmcnt(0) pre-barrier)

    // ---- stage C: wave 0 merges foreign quarters, sparsifies, emits
    if (wid == 0) {
#pragma unroll
        for (int r = 0; r < 4; ++r) {
            const int rowl = quad * 4 + r;
            float lv[5];
#pragma unroll
            for (int i = 0; i < 5; ++i) lv[i] = tv[r][i];
#pragma unroll
            for (int f = 0; f < 3; ++f) {
                float o[5];
#pragma unroll
                for (int i = 0; i < 5; ++i) o[i] = smv[f][rowl][i];
                merge5(lv, o);
            }

            // unpack cols from tags (positive score => tag was 4095-col)
            int t0 = __builtin_bit_cast(int, lv[0]);
            int t1 = __builtin_bit_cast(int, lv[1]);
            int t2 = __builtin_bit_cast(int, lv[2]);
            int t3 = __builtin_bit_cast(int, lv[3]);
            unsigned int i0 = (unsigned)((t0 & 4095) ^ (t0 >= 0 ? 4095 : 0));
            unsigned int i1 = (unsigned)((t1 & 4095) ^ (t1 >= 0 ? 4095 : 0));
            unsigned int i2 = (unsigned)((t2 & 4095) ^ (t2 >= 0 ? 4095 : 0));
            unsigned int i3 = (unsigned)((t3 & 4095) ^ (t3 >= 0 ? 4095 : 0));

            // sparsify, Z-free: w_i ∝ 2^(s_i - s_5) - 1 (tag noise <= 2^-12
            // relative on scores -> <0.2% on weights; tolerance is 1.6e-2)
            float u0 = exp2f(lv[0] - lv[4]) - 1.0f;
            float u1 = exp2f(lv[1] - lv[4]) - 1.0f;
            float u2 = exp2f(lv[2] - lv[4]) - 1.0f;
            float u3 = exp2f(lv[3] - lv[4]) - 1.0f;
            float inv = 1.0f / (u0 + u1 + u2 + u3 + 1e-30f);
            float w0 = u0 * inv, w1 = u1 * inv, w2 = u2 * inv, w3 = u3 * inv;

            const int rowabs = qbase + rowl;

            const float4 v0 = *(const float4*)(vb + (size_t)i0 * D + c16 * 4);
            const float4 v1 = *(const float4*)(vb + (size_t)i1 * D + c16 * 4);
            const float4 v2 = *(const float4*)(vb + (size_t)i2 * D + c16 * 4);
            const float4 v3 = *(const float4*)(vb + (size_t)i3 * D + c16 * 4);
            float4 o;
            o.x = w0 * v0.x + w1 * v1.x + w2 * v2.x + w3 * v3.x;
            o.y = w0 * v0.y + w1 * v1.y + w2 * v2.y + w3 * v3.y;
            o.z = w0 * v0.z + w1 * v1.z + w2 * v2.z + w3 * v3.z;
            o.w = w0 * v0.w + w1 * v1.w + w2 * v2.w + w3 * v3.w;
            *(float4*)(outg + (size_t)rowabs * D + c16 * 4) = o;

            // scatter <=4 nonzeros into the (zeroed) dense attn row
            if (c16 < 4) {
                float wv = c16 == 0 ? w0 : c16 == 1 ? w1 : c16 == 2 ? w2 : w3;
                unsigned int cs = c16 == 0 ? i0 : c16 == 1 ? i1
                                : c16 == 2 ? i2 : i3;
                if (wv > 0.f)
                    attng[(size_t)rowabs * L + cs] = wv;
            }
        }
    }
}

extern "C" void kernel_launch(void* const* d_in, const int* in_sizes, int n_in,
                              void* d_out, int out_size, void* d_ws, size_t ws_size,
                              hipStream_t stream) {
    const float* q = (const float*)d_in[0];
    const float* k = (const float*)d_in[1];
    const float* v = (const float*)d_in[2];
    float* out = (float*)d_out;
    unsigned short* ws = (unsigned short*)d_ws;

    // 1) convert Q (pre-scaled) and K fp32 -> bf16 hi/lo planes in d_ws
    convert_kernel<<<2048, 256, 0, stream>>>(q, k, ws);

    // 2) barrier-free sparse attention: 16 rows x 4 col-quarter waves / block
    sparse_attn_kernel<<<1024, 256, 0, stream>>>(ws, v, out);
}

// Round 6
// 308.959 us; speedup vs baseline: 1.2191x; 1.0040x over previous
//
#include <hip/hip_runtime.h>
#include <math.h>

#define NB 4
#define L 4096
#define D 64
// ws layout (ushorts): qh[16384][64] | ql[16384][64] | K: per batch
// [plane hi/lo][cq 8][col 4096][8 bf16]  (batch stride 524288, plane 262144)
#define WS_QL 1048576
#define WS_K  2097152
#define KBS   524288
#define KPL   262144
// Q pre-scale: 1/TEMPERATURE * log2(e)  -> scores in log2 units (monotone)
#define QSCALE 0.1803368801111243f

typedef __attribute__((ext_vector_type(8))) short short8;   // 8 bf16 = 4 VGPRs
typedef __attribute__((ext_vector_type(4))) float floatx4;

// fp32 -> (hi, lo) bf16 pair: hi = RNE(x), lo = RNE(x - hi) (exact residual).
static __device__ inline ushort2 f2bf2(float x) {
    unsigned int u = __builtin_bit_cast(unsigned int, x);
    unsigned int uh = u + (0x7FFFu + ((u >> 16) & 1u));
    unsigned short h = (unsigned short)(uh >> 16);
    float hf = __builtin_bit_cast(float, (unsigned int)h << 16);
    float r = x - hf;
    unsigned int v = __builtin_bit_cast(unsigned int, r);
    unsigned short l = (unsigned short)((v + (0x7FFFu + ((v >> 16) & 1u))) >> 16);
    ushort2 p; p.x = h; p.y = l; return p;
}

// ---- pre-pass: Q (scaled) and K fp32 -> bf16 hi/lo planes in d_ws
__global__ __launch_bounds__(256)
void convert_kernel(const float* __restrict__ qg, const float* __restrict__ kg,
                    unsigned short* __restrict__ ws) {
    unsigned int i = blockIdx.x * 256 + threadIdx.x;       // 524288 threads
    if (i < 262144) {                                      // Q: 262144 float4
        float4 qv = ((const float4*)qg)[i];
        ushort2 p0 = f2bf2(qv.x * QSCALE), p1 = f2bf2(qv.y * QSCALE),
                p2 = f2bf2(qv.z * QSCALE), p3 = f2bf2(qv.w * QSCALE);
        ushort4 h; h.x = p0.x; h.y = p1.x; h.z = p2.x; h.w = p3.x;
        ushort4 l; l.x = p0.y; l.y = p1.y; l.z = p2.y; l.w = p3.y;
        *(ushort4*)&ws[i * 4] = h;
        *(ushort4*)&ws[WS_QL + i * 4] = l;
    } else {                                               // K: 262144 float4
        unsigned int j = i - 262144;
        float4 kv = ((const float4*)kg)[j];
        ushort2 p0 = f2bf2(kv.x), p1 = f2bf2(kv.y), p2 = f2bf2(kv.z), p3 = f2bf2(kv.w);
        ushort4 h; h.x = p0.x; h.y = p1.x; h.z = p2.x; h.w = p3.x;
        ushort4 l; l.x = p0.y; l.y = p1.y; l.z = p2.y; l.w = p3.y;
        unsigned int bcol = j >> 4;                        // b*4096 + col
        unsigned int f4   = j & 15;
        unsigned int b    = bcol >> 12, col = bcol & 4095;
        unsigned int cq   = f4 >> 1, half = f4 & 1;
        size_t base = WS_K + (size_t)b * KBS + ((size_t)cq * 4096 + col) * 8 + half * 4;
        *(ushort4*)&ws[base] = h;
        *(ushort4*)&ws[base + KPL] = l;
    }
}

// ---- tagged top-5 primitives ------------------------------------------------
// Scores carry their column in the low 12 mantissa bits (cleared first):
// tag = 4095-col for s>=0, col for s<0  => float order == (score, lowest col).
// Sorted-descending insert of one value: d0'=max(t,d0), dk'=med3(t,d(k-1),dk).
static __device__ inline void ins5(float d[5], float t) {
    float n0 = fmaxf(d[0], t);
    float n1 = __builtin_amdgcn_fmed3f(t, d[0], d[1]);
    float n2 = __builtin_amdgcn_fmed3f(t, d[1], d[2]);
    float n3 = __builtin_amdgcn_fmed3f(t, d[2], d[3]);
    float n4 = __builtin_amdgcn_fmed3f(t, d[3], d[4]);
    d[0] = n0; d[1] = n1; d[2] = n2; d[3] = n3; d[4] = n4;
}

// Merge a sorted-descending 5-list o into sorted d (top-5 of union).
static __device__ inline void merge5(float d[5], const float o[5]) {
#pragma unroll
    for (int j = 0; j < 5; ++j) {
        float t = o[j];
        float carry = d[j];
        d[j] = fmaxf(d[j], t);
#pragma unroll
        for (int k = j + 1; k < 5; ++k) {
            float pk = d[k];
            d[k] = __builtin_amdgcn_fmed3f(t, carry, d[k]);
            carry = pk;
        }
    }
}

// 32 rows/block, 8 waves = (row-half rh, col-quarter cq). Waves (0,cq) and
// (1,cq) read IDENTICAL K fragments -> per-CU L2 K-traffic halves vs the
// 16-row variant (the sole change from round 5; r5 measured 310 us).
__global__ __launch_bounds__(512, 4)
void sparse_attn_kernel(const unsigned short* __restrict__ ws,
                        const float* __restrict__ vg,
                        float* __restrict__ outg) {
    __shared__ float smv[2][3][16][5];  // [row-half][foreign cq][row][slot]

    const int tid  = threadIdx.x;
    const int lane = tid & 63;
    const int wid  = tid >> 6;          // 0..7
    const int cq   = wid & 3;           // column quarter
    const int rh   = wid >> 2;          // row half
    const int c16  = lane & 15;
    const int quad = lane >> 4;

    // XCD swizzle: consecutive sblk on one XCD (64 blocks/XCD, lockstep K window)
    const int sblk  = (blockIdx.x & 7) * 64 + (blockIdx.x >> 3);
    const int qbase = sblk * 32;        // 32 rows per block
    const int qbw   = qbase + rh * 16;  // this wave's 16-row group
    const int b     = qbase >> 12;      // 4096/32=128 blocks/batch, no straddle

    const unsigned short* qh   = ws;
    const unsigned short* ql   = ws + WS_QL;
    const unsigned short* kbat = ws + WS_K + (size_t)b * KBS;
    const float* vb = vg + (size_t)b * L * D;
    float* attng = outg + (size_t)NB * L * D;

    // ---- Q fragments (loop-invariant): A[m=c16][k=quad*8+j], two K-steps
    const int qrow = qbw + c16;
    const short8 a0h = *(const short8*)&qh[(size_t)qrow * 64 + quad * 8];
    const short8 a1h = *(const short8*)&qh[(size_t)qrow * 64 + 32 + quad * 8];
    const short8 a0l = *(const short8*)&ql[(size_t)qrow * 64 + quad * 8];
    const short8 a1l = *(const short8*)&ql[(size_t)qrow * 64 + 32 + quad * 8];

    float tv[4][5];                     // tagged top-5 per row (sorted desc)
#pragma unroll
    for (int r = 0; r < 4; ++r)
#pragma unroll
        for (int i = 0; i < 5; ++i) tv[r][i] = -INFINITY;

    // Per-wave column quarter; K fragment base pointers (b128, coalesced).
    const int colq = cq * 1024;
    const int colbase = colq + c16;     // this lane's col for cg=0
    const unsigned short* bp0 = kbat + ((size_t)(quad)     * 4096 + colq + c16) * 8;
    const unsigned short* bp1 = kbat + ((size_t)(4 + quad) * 4096 + colq + c16) * 8;
    const float4 zv = make_float4(0.f, 0.f, 0.f, 0.f);

    // ---- barrier-free hot loop: 64 groups of 16 columns
#pragma unroll 4
    for (int cg = 0; cg < 64; ++cg) {
        const int off = cg * 128;                   // 16 cols * 8 ushorts
        short8 b0h = *(const short8*)(bp0 + off);
        short8 b1h = *(const short8*)(bp1 + off);
        short8 b0l = *(const short8*)(bp0 + KPL + off);
        short8 b1l = *(const short8*)(bp1 + KPL + off);
        floatx4 acc = {0.f, 0.f, 0.f, 0.f};
        acc = __builtin_amdgcn_mfma_f32_16x16x32_bf16(a0h, b0h, acc, 0, 0, 0);
        acc = __builtin_amdgcn_mfma_f32_16x16x32_bf16(a1h, b1h, acc, 0, 0, 0);
        acc = __builtin_amdgcn_mfma_f32_16x16x32_bf16(a0l, b0h, acc, 0, 0, 0);
        acc = __builtin_amdgcn_mfma_f32_16x16x32_bf16(a1l, b1h, acc, 0, 0, 0);
        acc = __builtin_amdgcn_mfma_f32_16x16x32_bf16(a0h, b0l, acc, 0, 0, 0);
        acc = __builtin_amdgcn_mfma_f32_16x16x32_bf16(a1h, b1l, acc, 0, 0, 0);

        // zero-fill one float4 of this wave's 16-row attn region (overlaps)
        {
            int idx = cg * 64 + lane;               // [0, 4096)
            *(float4*)&attng[(size_t)(qbw + (idx >> 8)) * L + colq + (idx & 255) * 4] = zv;
        }

        const int cx = (colbase + cg * 16) ^ 4095;  // tag for s >= 0
#pragma unroll
        for (int r = 0; r < 4; ++r) {
            int si  = __builtin_bit_cast(int, (float)acc[r]);
            int tag = cx ^ ((si >> 31) & 4095);     // s<0: tag flips back to col
            int ti  = (si & 0xFFFFF000) | tag;
            ins5(tv[r], __builtin_bit_cast(float, ti));
        }
    }

    // ---- stage A: butterfly merge across the 16 lanes of each quad
#pragma unroll
    for (int r = 0; r < 4; ++r) {
#pragma unroll
        for (int m = 8; m >= 1; m >>= 1) {
            float o[5];
#pragma unroll
            for (int i = 0; i < 5; ++i) o[i] = __shfl_xor(tv[r][i], m, 64);
            merge5(tv[r], o);
        }
    }

    // ---- stage B: cq 1-3 waves deposit per-row tagged lists
    if (cq > 0) {
#pragma unroll
        for (int r = 0; r < 4; ++r) {
            const int rowl = quad * 4 + r;
            if (c16 < 5) smv[rh][cq - 1][rowl][c16] = tv[r][c16];
        }
    }
    __syncthreads();    // also drains all zero-fill stores (vmcnt(0) pre-barrier)

    // ---- stage C: cq==0 wave of each row-half merges, sparsifies, emits
    if (cq == 0) {
#pragma unroll
        for (int r = 0; r < 4; ++r) {
            const int rowl = quad * 4 + r;
            float lv[5];
#pragma unroll
            for (int i = 0; i < 5; ++i) lv[i] = tv[r][i];
#pragma unroll
            for (int f = 0; f < 3; ++f) {
                float o[5];
#pragma unroll
                for (int i = 0; i < 5; ++i) o[i] = smv[rh][f][rowl][i];
                merge5(lv, o);
            }

            // unpack cols from tags (positive score => tag was 4095-col)
            int t0 = __builtin_bit_cast(int, lv[0]);
            int t1 = __builtin_bit_cast(int, lv[1]);
            int t2 = __builtin_bit_cast(int, lv[2]);
            int t3 = __builtin_bit_cast(int, lv[3]);
            unsigned int i0 = (unsigned)((t0 & 4095) ^ (t0 >= 0 ? 4095 : 0));
            unsigned int i1 = (unsigned)((t1 & 4095) ^ (t1 >= 0 ? 4095 : 0));
            unsigned int i2 = (unsigned)((t2 & 4095) ^ (t2 >= 0 ? 4095 : 0));
            unsigned int i3 = (unsigned)((t3 & 4095) ^ (t3 >= 0 ? 4095 : 0));

            // sparsify, Z-free: w_i ∝ 2^(s_i - s_5) - 1 (tag noise <= 2^-12
            // relative on scores -> small vs tolerance)
            float u0 = exp2f(lv[0] - lv[4]) - 1.0f;
            float u1 = exp2f(lv[1] - lv[4]) - 1.0f;
            float u2 = exp2f(lv[2] - lv[4]) - 1.0f;
            float u3 = exp2f(lv[3] - lv[4]) - 1.0f;
            float inv = 1.0f / (u0 + u1 + u2 + u3 + 1e-30f);
            float w0 = u0 * inv, w1 = u1 * inv, w2 = u2 * inv, w3 = u3 * inv;

            const int rowabs = qbw + rowl;

            const float4 v0 = *(const float4*)(vb + (size_t)i0 * D + c16 * 4);
            const float4 v1 = *(const float4*)(vb + (size_t)i1 * D + c16 * 4);
            const float4 v2 = *(const float4*)(vb + (size_t)i2 * D + c16 * 4);
            const float4 v3 = *(const float4*)(vb + (size_t)i3 * D + c16 * 4);
            float4 o;
            o.x = w0 * v0.x + w1 * v1.x + w2 * v2.x + w3 * v3.x;
            o.y = w0 * v0.y + w1 * v1.y + w2 * v2.y + w3 * v3.y;
            o.z = w0 * v0.z + w1 * v1.z + w2 * v2.z + w3 * v3.z;
            o.w = w0 * v0.w + w1 * v1.w + w2 * v2.w + w3 * v3.w;
            *(float4*)(outg + (size_t)rowabs * D + c16 * 4) = o;

            // scatter <=4 nonzeros into the (zeroed) dense attn row
            if (c16 < 4) {
                float wv = c16 == 0 ? w0 : c16 == 1 ? w1 : c16 == 2 ? w2 : w3;
                unsigned int cs = c16 == 0 ? i0 : c16 == 1 ? i1
                                : c16 == 2 ? i2 : i3;
                if (wv > 0.f)
                    attng[(size_t)rowabs * L + cs] = wv;
            }
        }
    }
}

extern "C" void kernel_launch(void* const* d_in, const int* in_sizes, int n_in,
                              void* d_out, int out_size, void* d_ws, size_t ws_size,
                              hipStream_t stream) {
    const float* q = (const float*)d_in[0];
    const float* k = (const float*)d_in[1];
    const float* v = (const float*)d_in[2];
    float* out = (float*)d_out;
    unsigned short* ws = (unsigned short*)d_ws;

    // 1) convert Q (pre-scaled) and K fp32 -> bf16 hi/lo planes in d_ws
    convert_kernel<<<2048, 256, 0, stream>>>(q, k, ws);

    // 2) barrier-free sparse attention: 32 rows x (2 row-half x 4 col-quarter)
    sparse_attn_kernel<<<512, 512, 0, stream>>>(ws, v, out);
}

// Round 7
// 304.626 us; speedup vs baseline: 1.2364x; 1.0142x over previous
//
#include <hip/hip_runtime.h>
#include <math.h>

#define NB 4
#define L 4096
#define D 64
// ws layout (ushorts): qh[16384][64] | ql[16384][64] | K: per batch
// [plane hi/lo][cq 8][col 4096][8 bf16]  (batch stride 524288, plane 262144)
#define WS_QL 1048576
#define WS_K  2097152
#define KBS   524288
#define KPL   262144
// Q pre-scale: 1/TEMPERATURE * log2(e)  -> scores in log2 units (monotone)
#define QSCALE 0.1803368801111243f

typedef __attribute__((ext_vector_type(8))) short short8;   // 8 bf16 = 4 VGPRs
typedef __attribute__((ext_vector_type(4))) float floatx4;

// fp32 -> (hi, lo) bf16 pair: hi = RNE(x), lo = RNE(x - hi) (exact residual).
static __device__ inline ushort2 f2bf2(float x) {
    unsigned int u = __builtin_bit_cast(unsigned int, x);
    unsigned int uh = u + (0x7FFFu + ((u >> 16) & 1u));
    unsigned short h = (unsigned short)(uh >> 16);
    float hf = __builtin_bit_cast(float, (unsigned int)h << 16);
    float r = x - hf;
    unsigned int v = __builtin_bit_cast(unsigned int, r);
    unsigned short l = (unsigned short)((v + (0x7FFFu + ((v >> 16) & 1u))) >> 16);
    ushort2 p; p.x = h; p.y = l; return p;
}

// ---- pre-pass: Q (scaled) and K fp32 -> bf16 hi/lo planes in d_ws
__global__ __launch_bounds__(256)
void convert_kernel(const float* __restrict__ qg, const float* __restrict__ kg,
                    unsigned short* __restrict__ ws) {
    unsigned int i = blockIdx.x * 256 + threadIdx.x;       // 524288 threads
    if (i < 262144) {                                      // Q: 262144 float4
        float4 qv = ((const float4*)qg)[i];
        ushort2 p0 = f2bf2(qv.x * QSCALE), p1 = f2bf2(qv.y * QSCALE),
                p2 = f2bf2(qv.z * QSCALE), p3 = f2bf2(qv.w * QSCALE);
        ushort4 h; h.x = p0.x; h.y = p1.x; h.z = p2.x; h.w = p3.x;
        ushort4 l; l.x = p0.y; l.y = p1.y; l.z = p2.y; l.w = p3.y;
        *(ushort4*)&ws[i * 4] = h;
        *(ushort4*)&ws[WS_QL + i * 4] = l;
    } else {                                               // K: 262144 float4
        unsigned int j = i - 262144;
        float4 kv = ((const float4*)kg)[j];
        ushort2 p0 = f2bf2(kv.x), p1 = f2bf2(kv.y), p2 = f2bf2(kv.z), p3 = f2bf2(kv.w);
        ushort4 h; h.x = p0.x; h.y = p1.x; h.z = p2.x; h.w = p3.x;
        ushort4 l; l.x = p0.y; l.y = p1.y; l.z = p2.y; l.w = p3.y;
        unsigned int bcol = j >> 4;                        // b*4096 + col
        unsigned int f4   = j & 15;
        unsigned int b    = bcol >> 12, col = bcol & 4095;
        unsigned int cq   = f4 >> 1, half = f4 & 1;
        size_t base = WS_K + (size_t)b * KBS + ((size_t)cq * 4096 + col) * 8 + half * 4;
        *(ushort4*)&ws[base] = h;
        *(ushort4*)&ws[base + KPL] = l;
    }
}

// ---- tagged top-5 primitives ------------------------------------------------
// Scores carry their column in the low 12 mantissa bits (cleared first):
// tag = 4095-col for s>=0, col for s<0  => float order == (score, lowest col).
// Sorted-descending insert of one value: d0'=max(t,d0), dk'=med3(t,d(k-1),dk).
// Order-insensitive: the final top-5 set is independent of insertion order,
// which is what makes the per-block loop-phase rotation legal.
static __device__ inline void ins5(float d[5], float t) {
    float n0 = fmaxf(d[0], t);
    float n1 = __builtin_amdgcn_fmed3f(t, d[0], d[1]);
    float n2 = __builtin_amdgcn_fmed3f(t, d[1], d[2]);
    float n3 = __builtin_amdgcn_fmed3f(t, d[2], d[3]);
    float n4 = __builtin_amdgcn_fmed3f(t, d[3], d[4]);
    d[0] = n0; d[1] = n1; d[2] = n2; d[3] = n3; d[4] = n4;
}

// Merge a sorted-descending 5-list o into sorted d (top-5 of union).
static __device__ inline void merge5(float d[5], const float o[5]) {
#pragma unroll
    for (int j = 0; j < 5; ++j) {
        float t = o[j];
        float carry = d[j];
        d[j] = fmaxf(d[j], t);
#pragma unroll
        for (int k = j + 1; k < 5; ++k) {
            float pk = d[k];
            d[k] = __builtin_amdgcn_fmed3f(t, carry, d[k]);
            carry = pk;
        }
    }
}

// 32 rows/block, 8 waves = (row-half rh, col-quarter cq). Per-block PHASE
// ROTATION of the cg loop: the 64 blocks of an XCD start at 64 different
// column windows, so concurrent L2 requests spread across the whole 1 MB
// K panel instead of serializing on one hot 16 KB window (same-line L2
// serialization was the remaining stall candidate after r1/r2/r4/r6
// excluded write-thrash, load-prefetch, store-coupling, and L2 read BW).
__global__ __launch_bounds__(512, 4)
void sparse_attn_kernel(const unsigned short* __restrict__ ws,
                        const float* __restrict__ vg,
                        float* __restrict__ outg) {
    __shared__ float smv[2][3][16][5];  // [row-half][foreign cq][row][slot]

    const int tid  = threadIdx.x;
    const int lane = tid & 63;
    const int wid  = tid >> 6;          // 0..7
    const int cq   = wid & 3;           // column quarter
    const int rh   = wid >> 2;          // row half
    const int c16  = lane & 15;
    const int quad = lane >> 4;

    // XCD swizzle: consecutive sblk on one XCD (64 blocks/XCD)
    const int sblk  = (blockIdx.x & 7) * 64 + (blockIdx.x >> 3);
    const int qbase = sblk * 32;        // 32 rows per block
    const int qbw   = qbase + rh * 16;  // this wave's 16-row group
    const int b     = qbase >> 12;      // 128 blocks/batch, no straddle
    const int phase = sblk & 63;        // distinct per block within an XCD

    const unsigned short* qh   = ws;
    const unsigned short* ql   = ws + WS_QL;
    const unsigned short* kbat = ws + WS_K + (size_t)b * KBS;
    const float* vb = vg + (size_t)b * L * D;
    float* attng = outg + (size_t)NB * L * D;

    // ---- Q fragments (loop-invariant): A[m=c16][k=quad*8+j], two K-steps
    const int qrow = qbw + c16;
    const short8 a0h = *(const short8*)&qh[(size_t)qrow * 64 + quad * 8];
    const short8 a1h = *(const short8*)&qh[(size_t)qrow * 64 + 32 + quad * 8];
    const short8 a0l = *(const short8*)&ql[(size_t)qrow * 64 + quad * 8];
    const short8 a1l = *(const short8*)&ql[(size_t)qrow * 64 + 32 + quad * 8];

    float tv[4][5];                     // tagged top-5 per row (sorted desc)
#pragma unroll
    for (int r = 0; r < 4; ++r)
#pragma unroll
        for (int i = 0; i < 5; ++i) tv[r][i] = -INFINITY;

    // Per-wave column quarter; K fragment base pointers (b128, coalesced).
    const int colq = cq * 1024;
    const int colbase = colq + c16;     // this lane's col for cg=0
    const unsigned short* bp0 = kbat + ((size_t)(quad)     * 4096 + colq + c16) * 8;
    const unsigned short* bp1 = kbat + ((size_t)(4 + quad) * 4096 + colq + c16) * 8;
    const float4 zv = make_float4(0.f, 0.f, 0.f, 0.f);

    // ---- barrier-free hot loop: 64 groups of 16 columns, phase-rotated
#pragma unroll 4
    for (int cg0 = 0; cg0 < 64; ++cg0) {
        int cg = cg0 + phase;
        cg = (cg >= 64) ? cg - 64 : cg;             // rotate, wrap

        const int off = cg * 128;                   // 16 cols * 8 ushorts
        short8 b0h = *(const short8*)(bp0 + off);
        short8 b1h = *(const short8*)(bp1 + off);
        short8 b0l = *(const short8*)(bp0 + KPL + off);
        short8 b1l = *(const short8*)(bp1 + KPL + off);
        floatx4 acc = {0.f, 0.f, 0.f, 0.f};
        acc = __builtin_amdgcn_mfma_f32_16x16x32_bf16(a0h, b0h, acc, 0, 0, 0);
        acc = __builtin_amdgcn_mfma_f32_16x16x32_bf16(a1h, b1h, acc, 0, 0, 0);
        acc = __builtin_amdgcn_mfma_f32_16x16x32_bf16(a0l, b0h, acc, 0, 0, 0);
        acc = __builtin_amdgcn_mfma_f32_16x16x32_bf16(a1l, b1h, acc, 0, 0, 0);
        acc = __builtin_amdgcn_mfma_f32_16x16x32_bf16(a0h, b0l, acc, 0, 0, 0);
        acc = __builtin_amdgcn_mfma_f32_16x16x32_bf16(a1h, b1l, acc, 0, 0, 0);

        // zero-fill one float4 of this wave's 16-row attn region (bijective
        // over the 64 rotated iterations, same as the linear order)
        {
            int idx = cg * 64 + lane;               // [0, 4096)
            *(float4*)&attng[(size_t)(qbw + (idx >> 8)) * L + colq + (idx & 255) * 4] = zv;
        }

        const int cx = (colbase + cg * 16) ^ 4095;  // tag for s >= 0
#pragma unroll
        for (int r = 0; r < 4; ++r) {
            int si  = __builtin_bit_cast(int, (float)acc[r]);
            int tag = cx ^ ((si >> 31) & 4095);     // s<0: tag flips back to col
            int ti  = (si & 0xFFFFF000) | tag;
            ins5(tv[r], __builtin_bit_cast(float, ti));
        }
    }

    // ---- stage A: butterfly merge across the 16 lanes of each quad
#pragma unroll
    for (int r = 0; r < 4; ++r) {
#pragma unroll
        for (int m = 8; m >= 1; m >>= 1) {
            float o[5];
#pragma unroll
            for (int i = 0; i < 5; ++i) o[i] = __shfl_xor(tv[r][i], m, 64);
            merge5(tv[r], o);
        }
    }

    // ---- stage B: cq 1-3 waves deposit per-row tagged lists
    if (cq > 0) {
#pragma unroll
        for (int r = 0; r < 4; ++r) {
            const int rowl = quad * 4 + r;
            if (c16 < 5) smv[rh][cq - 1][rowl][c16] = tv[r][c16];
        }
    }
    __syncthreads();    // also drains all zero-fill stores (vmcnt(0) pre-barrier)

    // ---- stage C: cq==0 wave of each row-half merges, sparsifies, emits
    if (cq == 0) {
#pragma unroll
        for (int r = 0; r < 4; ++r) {
            const int rowl = quad * 4 + r;
            float lv[5];
#pragma unroll
            for (int i = 0; i < 5; ++i) lv[i] = tv[r][i];
#pragma unroll
            for (int f = 0; f < 3; ++f) {
                float o[5];
#pragma unroll
                for (int i = 0; i < 5; ++i) o[i] = smv[rh][f][rowl][i];
                merge5(lv, o);
            }

            // unpack cols from tags (positive score => tag was 4095-col)
            int t0 = __builtin_bit_cast(int, lv[0]);
            int t1 = __builtin_bit_cast(int, lv[1]);
            int t2 = __builtin_bit_cast(int, lv[2]);
            int t3 = __builtin_bit_cast(int, lv[3]);
            unsigned int i0 = (unsigned)((t0 & 4095) ^ (t0 >= 0 ? 4095 : 0));
            unsigned int i1 = (unsigned)((t1 & 4095) ^ (t1 >= 0 ? 4095 : 0));
            unsigned int i2 = (unsigned)((t2 & 4095) ^ (t2 >= 0 ? 4095 : 0));
            unsigned int i3 = (unsigned)((t3 & 4095) ^ (t3 >= 0 ? 4095 : 0));

            // sparsify, Z-free: w_i ∝ 2^(s_i - s_5) - 1 (tag noise <= 2^-12
            // relative on scores -> small vs tolerance)
            float u0 = exp2f(lv[0] - lv[4]) - 1.0f;
            float u1 = exp2f(lv[1] - lv[4]) - 1.0f;
            float u2 = exp2f(lv[2] - lv[4]) - 1.0f;
            float u3 = exp2f(lv[3] - lv[4]) - 1.0f;
            float inv = 1.0f / (u0 + u1 + u2 + u3 + 1e-30f);
            float w0 = u0 * inv, w1 = u1 * inv, w2 = u2 * inv, w3 = u3 * inv;

            const int rowabs = qbw + rowl;

            const float4 v0 = *(const float4*)(vb + (size_t)i0 * D + c16 * 4);
            const float4 v1 = *(const float4*)(vb + (size_t)i1 * D + c16 * 4);
            const float4 v2 = *(const float4*)(vb + (size_t)i2 * D + c16 * 4);
            const float4 v3 = *(const float4*)(vb + (size_t)i3 * D + c16 * 4);
            float4 o;
            o.x = w0 * v0.x + w1 * v1.x + w2 * v2.x + w3 * v3.x;
            o.y = w0 * v0.y + w1 * v1.y + w2 * v2.y + w3 * v3.y;
            o.z = w0 * v0.z + w1 * v1.z + w2 * v2.z + w3 * v3.z;
            o.w = w0 * v0.w + w1 * v1.w + w2 * v2.w + w3 * v3.w;
            *(float4*)(outg + (size_t)rowabs * D + c16 * 4) = o;

            // scatter <=4 nonzeros into the (zeroed) dense attn row
            if (c16 < 4) {
                float wv = c16 == 0 ? w0 : c16 == 1 ? w1 : c16 == 2 ? w2 : w3;
                unsigned int cs = c16 == 0 ? i0 : c16 == 1 ? i1
                                : c16 == 2 ? i2 : i3;
                if (wv > 0.f)
                    attng[(size_t)rowabs * L + cs] = wv;
            }
        }
    }
}

extern "C" void kernel_launch(void* const* d_in, const int* in_sizes, int n_in,
                              void* d_out, int out_size, void* d_ws, size_t ws_size,
                              hipStream_t stream) {
    const float* q = (const float*)d_in[0];
    const float* k = (const float*)d_in[1];
    const float* v = (const float*)d_in[2];
    float* out = (float*)d_out;
    unsigned short* ws = (unsigned short*)d_ws;

    // 1) convert Q (pre-scaled) and K fp32 -> bf16 hi/lo planes in d_ws
    convert_kernel<<<2048, 256, 0, stream>>>(q, k, ws);

    // 2) barrier-free sparse attention: 32 rows x (2 row-half x 4 col-quarter)
    sparse_attn_kernel<<<512, 512, 0, stream>>>(ws, v, out);
}

// Round 8
// 303.044 us; speedup vs baseline: 1.2428x; 1.0052x over previous
//
#include <hip/hip_runtime.h>
#include <math.h>

#define NB 4
#define L 4096
#define D 64
// ws layout (ushorts): qh[16384][64] | ql[16384][64] | K: per batch
// [plane hi/lo][cq 8][col 4096][8 bf16]  (batch stride 524288, plane 262144)
#define WS_QL 1048576
#define WS_K  2097152
#define KBS   524288
#define KPL   262144
// Q pre-scale: 1/TEMPERATURE * log2(e)  -> scores in log2 units (monotone)
#define QSCALE 0.1803368801111243f

typedef __attribute__((ext_vector_type(8))) short short8;   // 8 bf16 = 4 VGPRs
typedef __attribute__((ext_vector_type(4))) float floatx4;

// fp32 -> (hi, lo) bf16 pair: hi = RNE(x), lo = RNE(x - hi) (exact residual).
static __device__ inline ushort2 f2bf2(float x) {
    unsigned int u = __builtin_bit_cast(unsigned int, x);
    unsigned int uh = u + (0x7FFFu + ((u >> 16) & 1u));
    unsigned short h = (unsigned short)(uh >> 16);
    float hf = __builtin_bit_cast(float, (unsigned int)h << 16);
    float r = x - hf;
    unsigned int v = __builtin_bit_cast(unsigned int, r);
    unsigned short l = (unsigned short)((v + (0x7FFFu + ((v >> 16) & 1u))) >> 16);
    ushort2 p; p.x = h; p.y = l; return p;
}

// ---- pre-pass: Q (scaled) and K fp32 -> bf16 hi/lo planes in d_ws
__global__ __launch_bounds__(256)
void convert_kernel(const float* __restrict__ qg, const float* __restrict__ kg,
                    unsigned short* __restrict__ ws) {
    unsigned int i = blockIdx.x * 256 + threadIdx.x;       // 524288 threads
    if (i < 262144) {                                      // Q: 262144 float4
        float4 qv = ((const float4*)qg)[i];
        ushort2 p0 = f2bf2(qv.x * QSCALE), p1 = f2bf2(qv.y * QSCALE),
                p2 = f2bf2(qv.z * QSCALE), p3 = f2bf2(qv.w * QSCALE);
        ushort4 h; h.x = p0.x; h.y = p1.x; h.z = p2.x; h.w = p3.x;
        ushort4 l; l.x = p0.y; l.y = p1.y; l.z = p2.y; l.w = p3.y;
        *(ushort4*)&ws[i * 4] = h;
        *(ushort4*)&ws[WS_QL + i * 4] = l;
    } else {                                               // K: 262144 float4
        unsigned int j = i - 262144;
        float4 kv = ((const float4*)kg)[j];
        ushort2 p0 = f2bf2(kv.x), p1 = f2bf2(kv.y), p2 = f2bf2(kv.z), p3 = f2bf2(kv.w);
        ushort4 h; h.x = p0.x; h.y = p1.x; h.z = p2.x; h.w = p3.x;
        ushort4 l; l.x = p0.y; l.y = p1.y; l.z = p2.y; l.w = p3.y;
        unsigned int bcol = j >> 4;                        // b*4096 + col
        unsigned int f4   = j & 15;
        unsigned int b    = bcol >> 12, col = bcol & 4095;
        unsigned int cq   = f4 >> 1, half = f4 & 1;
        size_t base = WS_K + (size_t)b * KBS + ((size_t)cq * 4096 + col) * 8 + half * 4;
        *(ushort4*)&ws[base] = h;
        *(ushort4*)&ws[base + KPL] = l;
    }
}

// ---- tagged top-5 primitives ------------------------------------------------
// Scores carry their column in the low 12 mantissa bits (cleared first):
// tag = 4095-col for s>=0, col for s<0  => float order == (score, lowest col).
// Sorted-descending insert of one value: d0'=max(t,d0), dk'=med3(t,d(k-1),dk).
static __device__ inline void ins5(float d[5], float t) {
    float n0 = fmaxf(d[0], t);
    float n1 = __builtin_amdgcn_fmed3f(t, d[0], d[1]);
    float n2 = __builtin_amdgcn_fmed3f(t, d[1], d[2]);
    float n3 = __builtin_amdgcn_fmed3f(t, d[2], d[3]);
    float n4 = __builtin_amdgcn_fmed3f(t, d[3], d[4]);
    d[0] = n0; d[1] = n1; d[2] = n2; d[3] = n3; d[4] = n4;
}

// Merge a sorted-descending 5-list o into sorted d (top-5 of union).
static __device__ inline void merge5(float d[5], const float o[5]) {
#pragma unroll
    for (int j = 0; j < 5; ++j) {
        float t = o[j];
        float carry = d[j];
        d[j] = fmaxf(d[j], t);
#pragma unroll
        for (int k = j + 1; k < 5; ++k) {
            float pk = d[k];
            d[k] = __builtin_amdgcn_fmed3f(t, carry, d[k]);
            carry = pk;
        }
    }
}

// 32 rows/block, 8 waves = (row-half rh, col-quarter cq).
// OPERAND-SWAPPED MFMA: compute K*Q^T (A=K frag, B=Q frag — identical per-lane
// fragment layouts, so only the intrinsic args swap). C layout then gives each
// lane 4 scores of ONE Q-row (n=c16): top-5 state is tv[5] (5 VGPRs) instead
// of tv[4][5] (20) — r5 showed register pressure is the binding constraint.
__global__ __launch_bounds__(512, 4)
void sparse_attn_kernel(const unsigned short* __restrict__ ws,
                        const float* __restrict__ vg,
                        float* __restrict__ outg) {
    __shared__ float smv[2][4][16][5];  // [row-half][cq][row][slot]

    const int tid  = threadIdx.x;
    const int lane = tid & 63;
    const int wid  = tid >> 6;          // 0..7
    const int cq   = wid & 3;           // column quarter
    const int rh   = wid >> 2;          // row half
    const int c16  = lane & 15;
    const int quad = lane >> 4;

    // XCD swizzle: consecutive sblk on one XCD (64 blocks/XCD)
    const int sblk  = (blockIdx.x & 7) * 64 + (blockIdx.x >> 3);
    const int qbase = sblk * 32;        // 32 rows per block
    const int qbw   = qbase + rh * 16;  // this wave's 16-row group
    const int b     = qbase >> 12;      // 128 blocks/batch, no straddle
    const int phase = sblk & 63;        // distinct per block within an XCD

    const unsigned short* qh   = ws;
    const unsigned short* ql   = ws + WS_QL;
    const unsigned short* kbat = ws + WS_K + (size_t)b * KBS;
    const float* vb = vg + (size_t)b * L * D;
    float* attng = outg + (size_t)NB * L * D;

    // ---- Q fragments (loop-invariant), used as the B operand after the swap
    const int qrow = qbw + c16;
    const short8 a0h = *(const short8*)&qh[(size_t)qrow * 64 + quad * 8];
    const short8 a1h = *(const short8*)&qh[(size_t)qrow * 64 + 32 + quad * 8];
    const short8 a0l = *(const short8*)&ql[(size_t)qrow * 64 + quad * 8];
    const short8 a1l = *(const short8*)&ql[(size_t)qrow * 64 + 32 + quad * 8];

    float tv[5];                        // tagged top-5 for row c16 (sorted desc)
#pragma unroll
    for (int i = 0; i < 5; ++i) tv[i] = -INFINITY;

    // Per-wave column quarter; K fragment base pointers (b128, coalesced).
    const int colq = cq * 1024;
    const unsigned short* bp0 = kbat + ((size_t)(quad)     * 4096 + colq + c16) * 8;
    const unsigned short* bp1 = kbat + ((size_t)(4 + quad) * 4096 + colq + c16) * 8;
    const float4 zv = make_float4(0.f, 0.f, 0.f, 0.f);

    // this lane's col base (r=0) as a function of cg: colq + cg*16 + quad*4
    const int colb0 = colq + quad * 4;

    // ---- barrier-free hot loop: 64 groups of 16 columns, phase-rotated
#pragma unroll 4
    for (int cg0 = 0; cg0 < 64; ++cg0) {
        int cg = cg0 + phase;
        cg = (cg >= 64) ? cg - 64 : cg;             // rotate, wrap

        const int off = cg * 128;                   // 16 cols * 8 ushorts
        short8 b0h = *(const short8*)(bp0 + off);
        short8 b1h = *(const short8*)(bp1 + off);
        short8 b0l = *(const short8*)(bp0 + KPL + off);
        short8 b1l = *(const short8*)(bp1 + KPL + off);
        floatx4 acc = {0.f, 0.f, 0.f, 0.f};
        // A=K, B=Q: Kh*Qh + Kh*Ql + Kl*Qh  (same products as before the swap)
        acc = __builtin_amdgcn_mfma_f32_16x16x32_bf16(b0h, a0h, acc, 0, 0, 0);
        acc = __builtin_amdgcn_mfma_f32_16x16x32_bf16(b1h, a1h, acc, 0, 0, 0);
        acc = __builtin_amdgcn_mfma_f32_16x16x32_bf16(b0h, a0l, acc, 0, 0, 0);
        acc = __builtin_amdgcn_mfma_f32_16x16x32_bf16(b1h, a1l, acc, 0, 0, 0);
        acc = __builtin_amdgcn_mfma_f32_16x16x32_bf16(b0l, a0h, acc, 0, 0, 0);
        acc = __builtin_amdgcn_mfma_f32_16x16x32_bf16(b1l, a1h, acc, 0, 0, 0);

        // zero-fill one float4 of this wave's 16-row attn region (bijective
        // over the 64 rotated iterations)
        {
            int idx = cg * 64 + lane;               // [0, 4096)
            *(float4*)&attng[(size_t)(qbw + (idx >> 8)) * L + colq + (idx & 255) * 4] = zv;
        }

        // cols for r=0..3: colb = colb0 + cg*16 + r (colb0+cg*16 ≡ 0 mod 4)
        // cx_r = (col_r)^4095 = cxb ^ r  (low 2 bits of cxb are 1s)
        const int cxb = (colb0 + cg * 16) ^ 4095;
#pragma unroll
        for (int r = 0; r < 4; ++r) {
            int si  = __builtin_bit_cast(int, (float)acc[r]);
            int tag = (cxb ^ r) ^ ((si >> 31) & 4095);  // s<0: flips to col
            int ti  = (si & 0xFFFFF000) | tag;
            ins5(tv, __builtin_bit_cast(float, ti));
        }
    }

    // ---- stage A: merge across the 4 quads (same row c16, disjoint cols)
#pragma unroll
    for (int m = 16; m <= 32; m <<= 1) {
        float o[5];
#pragma unroll
        for (int i = 0; i < 5; ++i) o[i] = __shfl_xor(tv[i], m, 64);
        merge5(tv, o);
    }

    // ---- stage B: every wave's quad-0 lanes deposit the 16 per-row lists
    if (quad == 0) {
#pragma unroll
        for (int i = 0; i < 5; ++i) smv[rh][cq][c16][i] = tv[i];
    }
    __syncthreads();    // also drains all zero-fill stores (vmcnt(0) pre-barrier)

    // ---- stage C: cq==0 wave of each row-half merges, sparsifies, emits
    if (cq == 0) {
#pragma unroll
        for (int r = 0; r < 4; ++r) {
            const int rowl = quad * 4 + r;
            float lv[5];
#pragma unroll
            for (int i = 0; i < 5; ++i) lv[i] = smv[rh][0][rowl][i];
#pragma unroll
            for (int f = 1; f < 4; ++f) {
                float o[5];
#pragma unroll
                for (int i = 0; i < 5; ++i) o[i] = smv[rh][f][rowl][i];
                merge5(lv, o);
            }

            // unpack cols from tags (positive score => tag was 4095-col)
            int t0 = __builtin_bit_cast(int, lv[0]);
            int t1 = __builtin_bit_cast(int, lv[1]);
            int t2 = __builtin_bit_cast(int, lv[2]);
            int t3 = __builtin_bit_cast(int, lv[3]);
            unsigned int i0 = (unsigned)((t0 & 4095) ^ (t0 >= 0 ? 4095 : 0));
            unsigned int i1 = (unsigned)((t1 & 4095) ^ (t1 >= 0 ? 4095 : 0));
            unsigned int i2 = (unsigned)((t2 & 4095) ^ (t2 >= 0 ? 4095 : 0));
            unsigned int i3 = (unsigned)((t3 & 4095) ^ (t3 >= 0 ? 4095 : 0));

            // sparsify, Z-free: w_i ∝ 2^(s_i - s_5) - 1 (tag noise <= 2^-12
            // relative on scores -> small vs tolerance)
            float u0 = exp2f(lv[0] - lv[4]) - 1.0f;
            float u1 = exp2f(lv[1] - lv[4]) - 1.0f;
            float u2 = exp2f(lv[2] - lv[4]) - 1.0f;
            float u3 = exp2f(lv[3] - lv[4]) - 1.0f;
            float inv = 1.0f / (u0 + u1 + u2 + u3 + 1e-30f);
            float w0 = u0 * inv, w1 = u1 * inv, w2 = u2 * inv, w3 = u3 * inv;

            const int rowabs = qbw + rowl;

            const float4 v0 = *(const float4*)(vb + (size_t)i0 * D + c16 * 4);
            const float4 v1 = *(const float4*)(vb + (size_t)i1 * D + c16 * 4);
            const float4 v2 = *(const float4*)(vb + (size_t)i2 * D + c16 * 4);
            const float4 v3 = *(const float4*)(vb + (size_t)i3 * D + c16 * 4);
            float4 o;
            o.x = w0 * v0.x + w1 * v1.x + w2 * v2.x + w3 * v3.x;
            o.y = w0 * v0.y + w1 * v1.y + w2 * v2.y + w3 * v3.y;
            o.z = w0 * v0.z + w1 * v1.z + w2 * v2.z + w3 * v3.z;
            o.w = w0 * v0.w + w1 * v1.w + w2 * v2.w + w3 * v3.w;
            *(float4*)(outg + (size_t)rowabs * D + c16 * 4) = o;

            // scatter <=4 nonzeros into the (zeroed) dense attn row
            if (c16 < 4) {
                float wv = c16 == 0 ? w0 : c16 == 1 ? w1 : c16 == 2 ? w2 : w3;
                unsigned int cs = c16 == 0 ? i0 : c16 == 1 ? i1
                                : c16 == 2 ? i2 : i3;
                if (wv > 0.f)
                    attng[(size_t)rowabs * L + cs] = wv;
            }
        }
    }
}

extern "C" void kernel_launch(void* const* d_in, const int* in_sizes, int n_in,
                              void* d_out, int out_size, void* d_ws, size_t ws_size,
                              hipStream_t stream) {
    const float* q = (const float*)d_in[0];
    const float* k = (const float*)d_in[1];
    const float* v = (const float*)d_in[2];
    float* out = (float*)d_out;
    unsigned short* ws = (unsigned short*)d_ws;

    // 1) convert Q (pre-scaled) and K fp32 -> bf16 hi/lo planes in d_ws
    convert_kernel<<<2048, 256, 0, stream>>>(q, k, ws);

    // 2) barrier-free sparse attention: 32 rows x (2 row-half x 4 col-quarter)
    sparse_attn_kernel<<<512, 512, 0, stream>>>(ws, v, out);
}